// Round 7
// baseline (450.830 us; speedup 1.0000x reference)
//
#include <hip/hip_runtime.h>
#include <hip/hip_bf16.h>
#include <hip/hip_fp16.h>

// DownEdgeMP, round 11: r10 structure + r5's PROVEN asm pk-f16 atomics + 4 blk/CU.
// r8-r10 post-mortem: unsafeAtomicAdd(__half2) does NOT emit a clean
// global_atomic_pk_add_f16 on this toolchain — WRITE_SIZE inflated 2-2.7x
// (212/287MB vs 112.5MB payload; r10 VGPR=48 rules out spill) => CAS/fallback
// loop: serialized retries poisoned r8/r9/r10. r5's inline-asm atomic measured
// clean (WRITE 112.5MB, 290us). This round: r10's swapped-operand no-hbuf
// kernel (32KB LDS, 9 barriers, 0 bank conflicts) + asm atomics + 4 blocks/CU
// (launch_bounds(256,4): VGPR cap 128 >> ~48 used; 4x32KB=128KB LDS).
// Swapped ops: D = W^T(LDS, A-operand) . x^T/h^T(regs, B-operand);
// pi(p)=32(s&3)+8kq+4(s>>2)+r baked into W0-out/W1-in cols at prep ->
// layer transition = in-lane pack(selu(acc[ks]),selu(acc[ks+4])). b0 baked
// into W0 row k=264 (const-1 input); b1 (pi-permuted) / b2 from global.
// Scatter: lane owns edge (col=ml), 16 pk-f16 atomics, issued after last
// barrier so no barrier drain ever waits on an atomic.

using u16    = unsigned short;
using u16x8  = __attribute__((ext_vector_type(8))) unsigned short;
using bf16x8 = __attribute__((ext_vector_type(8))) short;
using f32x4  = __attribute__((ext_vector_type(4))) float;

constexpr int H   = 128;
constexpr int NTH = 256;

__device__ __forceinline__ u16 f2bf(float f) {          // prep only
    union { float f; unsigned u; } x; x.f = f;
    unsigned r = x.u + 0x7FFFu + ((x.u >> 16) & 1u);
    return (u16)(r >> 16);
}
__device__ __forceinline__ unsigned cvt2(float x, float y) {
    union { __hip_bfloat162 h; unsigned u; } c;
    c.h = __float22bfloat162_rn(make_float2(x, y));     // v_cvt_pk_bf16_f32
    return c.u;
}
__device__ __forceinline__ bf16x8 cvt8(float4 a, float4 b) {
    union { unsigned u[4]; bf16x8 v; } o;
    o.u[0] = cvt2(a.x, a.y); o.u[1] = cvt2(a.z, a.w);
    o.u[2] = cvt2(b.x, b.y); o.u[3] = cvt2(b.z, b.w);
    return o.v;
}
__device__ __forceinline__ float4 ld4(const float* p) { return *(const float4*)p; }
__device__ __forceinline__ float h2f(u16 u) {
    union { u16 u; __half h; } c; c.u = u;
    return __half2float(c.h);
}
__device__ __forceinline__ float selu_f(float x) {
    const float scale = 1.0507009873554804934193349852946f;
    const float sa    = 1.0507009873554805f * 1.6732632423543772848170429916717f;
    return x > 0.0f ? scale * x : sa * (__expf(x) - 1.0f);
}
// pack(selu(a), selu(b)) -> bf16x8 : the entire layer transition
__device__ __forceinline__ bf16x8 cvt8selu(f32x4 a, f32x4 b) {
    union { unsigned u[4]; bf16x8 v; } o;
    o.u[0] = cvt2(selu_f(a[0]), selu_f(a[1]));
    o.u[1] = cvt2(selu_f(a[2]), selu_f(a[3]));
    o.u[2] = cvt2(selu_f(b[0]), selu_f(b[1]));
    o.u[3] = cvt2(selu_f(b[2]), selu_f(b[3]));
    return o.v;
}
__device__ __forceinline__ int pperm(int p) {           // pi
    int s = p >> 4, kq = (p >> 2) & 3, r = p & 3;
    return 32 * (s & 3) + 8 * kq + 4 * (s >> 2) + r;
}

// ---- weight chunk staging: 128 rows x 64 k (16 KB) ----
__device__ __forceinline__ void load_wchunk(const u16* __restrict__ wt, int KPu, int c,
                                            int tid, u16x8 st[4]) {
#pragma unroll
    for (int s = 0; s < 4; ++s) {
        int i = s * NTH + tid;                 // 0..1023
        int n = i >> 3, jj = i & 7;
        st[s] = *(const u16x8*)(wt + (size_t)n * KPu + (c * 8 + jj) * 8);
    }
}
__device__ __forceinline__ void write_wchunk(u16* wb, int tid, const u16x8 st[4]) {
#pragma unroll
    for (int s = 0; s < 4; ++s) {
        int i = s * NTH + tid;
        *(u16x8*)(wb + i * 8) = st[s];
    }
}

// canonical (edge_mlp): A = activations, B = weights from LDS
template<int NKS>
__device__ __forceinline__ void mfma_chunk(const u16* cur, const bf16x8* afc,
                                           int ml, int kq, f32x4 acc[8]) {
#pragma unroll
    for (int ks = 0; ks < NKS; ++ks) {
        bf16x8 a = afc[ks];
#pragma unroll
        for (int sc = 0; sc < 8; ++sc) {
            bf16x8 b = *(const bf16x8*)&cur[(sc * 16 + ml) * 64 +
                                            (((ks * 4 + kq) ^ (ml & 7)) << 3)];
            acc[sc] = __builtin_amdgcn_mfma_f32_16x16x32_bf16(a, b, acc[sc], 0, 0, 0);
        }
    }
}
// swapped (angle): A = weights from LDS, B = activations (cols = edges)
template<int NKS>
__device__ __forceinline__ void mfma_chunk_sw(const u16* cur, const bf16x8* bfc,
                                              int ml, int kq, f32x4 acc[8]) {
#pragma unroll
    for (int ks = 0; ks < NKS; ++ks) {
        bf16x8 b = bfc[ks];
#pragma unroll
        for (int sc = 0; sc < 8; ++sc) {
            bf16x8 a = *(const bf16x8*)&cur[(sc * 16 + ml) * 64 +
                                            (((ks * 4 + kq) ^ (ml & 7)) << 3)];
            acc[sc] = __builtin_amdgcn_mfma_f32_16x16x32_bf16(a, b, acc[sc], 0, 0, 0);
        }
    }
}

// stream NCHUNK 64-K chunks through double-buffered LDS (canonical / swapped)
template<int NCHUNK, int LAST_NKS>
__device__ __forceinline__ void stream_layer(const u16* __restrict__ wt, int KPu,
                                             const bf16x8* af, u16* wb0, u16* wb1,
                                             int tid, int ml, int kq, f32x4 acc[8]) {
    u16x8 st[4];
    load_wchunk(wt, KPu, 0, tid, st);
    write_wchunk(wb0, tid, st);
    __syncthreads();
#pragma unroll
    for (int c = 0; c < NCHUNK; ++c) {
        u16* cur = (c & 1) ? wb1 : wb0;
        u16* nxt = (c & 1) ? wb0 : wb1;
        if (c + 1 < NCHUNK) load_wchunk(wt, KPu, c + 1, tid, st);   // issue early
        if (c == NCHUNK - 1) mfma_chunk<LAST_NKS>(cur, af + 2 * c, ml, kq, acc);
        else                 mfma_chunk<2>(cur, af + 2 * c, ml, kq, acc);
        if (c + 1 < NCHUNK) write_wchunk(nxt, tid, st);             // write late
        __syncthreads();
    }
}
template<int NCHUNK, int LAST_NKS>
__device__ __forceinline__ void stream_layer_sw(const u16* __restrict__ wt, int KPu,
                                                const bf16x8* bf, u16* wb0, u16* wb1,
                                                int tid, int ml, int kq, f32x4 acc[8]) {
    u16x8 st[4];
    load_wchunk(wt, KPu, 0, tid, st);
    write_wchunk(wb0, tid, st);
    __syncthreads();
#pragma unroll
    for (int c = 0; c < NCHUNK; ++c) {
        u16* cur = (c & 1) ? wb1 : wb0;
        u16* nxt = (c & 1) ? wb0 : wb1;
        if (c + 1 < NCHUNK) load_wchunk(wt, KPu, c + 1, tid, st);
        if (c == NCHUNK - 1) mfma_chunk_sw<LAST_NKS>(cur, bf + 2 * c, ml, kq, acc);
        else                 mfma_chunk_sw<2>(cur, bf + 2 * c, ml, kq, acc);
        if (c + 1 < NCHUNK) write_wchunk(nxt, tid, st);
        __syncthreads();
    }
}

// K=128 layer: preload both 64-K chunks, single barrier
__device__ __forceinline__ void preload2_layer(const u16* __restrict__ wt,
                                               const bf16x8* af, u16* wb0, u16* wb1,
                                               int tid, int ml, int kq, f32x4 acc[8]) {
    u16x8 s0[4], s1[4];
    load_wchunk(wt, 128, 0, tid, s0);
    load_wchunk(wt, 128, 1, tid, s1);
    write_wchunk(wb0, tid, s0);
    write_wchunk(wb1, tid, s1);
    __syncthreads();
    mfma_chunk<2>(wb0, af + 0, ml, kq, acc);
    mfma_chunk<2>(wb1, af + 2, ml, kq, acc);
}
__device__ __forceinline__ void preload2_layer_sw(const u16* __restrict__ wt,
                                                  const bf16x8* bf, u16* wb0, u16* wb1,
                                                  int tid, int ml, int kq, f32x4 acc[8]) {
    u16x8 s0[4], s1[4];
    load_wchunk(wt, 128, 0, tid, s0);
    load_wchunk(wt, 128, 1, tid, s1);
    write_wchunk(wb0, tid, s0);
    write_wchunk(wb1, tid, s1);
    __syncthreads();
    mfma_chunk_sw<2>(wb0, bf + 0, ml, kq, acc);
    mfma_chunk_sw<2>(wb1, bf + 2, ml, kq, acc);
}

__device__ __forceinline__ void init_acc(const float* __restrict__ b, int ml, f32x4 acc[8]) {
#pragma unroll
    for (int sc = 0; sc < 8; ++sc) {
        float bv = b[sc * 16 + ml];
        acc[sc] = f32x4{bv, bv, bv, bv};
    }
}

// SELU(acc) -> bf16 -> hbuf[.][136] (edge_mlp path only)
__device__ __forceinline__ void store_h_selu(const f32x4 acc[8], u16* hbuf,
                                             int w, int ml, int kq) {
#pragma unroll
    for (int sc = 0; sc < 8; ++sc)
#pragma unroll
        for (int r = 0; r < 4; r += 2) {
            unsigned u = cvt2(selu_f(acc[sc][r]), selu_f(acc[sc][r + 1]));
            int rowb = w * 16 + kq * 4 + r;
            hbuf[rowb * 136 + sc * 16 + ml]       = (u16)u;
            hbuf[(rowb + 1) * 136 + sc * 16 + ml] = (u16)(u >> 16);
        }
}
__device__ __forceinline__ void read_af_h(const u16* hbuf, int w, int ml, int kq,
                                          bf16x8 af[4]) {
#pragma unroll
    for (int f = 0; f < 4; ++f)            // col = f*32 + kq*8
        af[f] = *(const bf16x8*)&hbuf[(w * 16 + ml) * 136 + f * 32 + kq * 8];
}

// ---- prep: fp32 W[K][128] -> bf16 W^T[128][KP], 16B-block XOR(n&7) swizzle.
// m=0 (aW0): col pi(n), bias ab0[pi(n)] injected at k=264.
// m=1 (aW1): col pi(n). m=2 (aW2), m>=3 (eW*): canonical.
// tail block: b1p[i] = ab1[pi(i)].
__global__ void prep_weights(const float* __restrict__ aW0, const float* __restrict__ ab0,
                             const float* __restrict__ aW1, const float* __restrict__ ab1,
                             const float* __restrict__ aW2, const float* __restrict__ eW0,
                             const float* __restrict__ eW1, const float* __restrict__ eW2,
                             u16* __restrict__ dst, float* __restrict__ b1p)
{
    int t = blockIdx.x * 256 + threadIdx.x;
    if (t >= 17408) {                       // tail: permuted b1
        int i = t - 17408;
        if (i < 128) b1p[i] = ab1[pperm(i)];
        return;
    }
    const int nbs[6]  = {40, 16, 16, 32, 16, 16};
    const int Ks[6]   = {264, 128, 128, 256, 128, 128};
    const int offs[6] = {0, 40960, 57344, 73728, 106496, 122880};
    const float* Ws[6] = {aW0, aW1, aW2, eW0, eW1, eW2};
    int m = 0, rem = t;
    for (m = 0; m < 6; ++m) { int c = 128 * nbs[m]; if (rem < c) break; rem -= c; }
    if (m >= 6) return;
    const int nb = nbs[m];
    const int n = rem / nb, j = rem % nb;
    const int c = j >> 3, jj = j & 7;
    const int kb = jj ^ (n & 7);
    const int k0 = c * 64 + kb * 8;
    const int K = Ks[m];
    const float* W = Ws[m];
    const int nc = (m <= 1) ? pperm(n) : n;
    union { u16 u[8]; u16x8 v; } o;
#pragma unroll
    for (int i = 0; i < 8; ++i) {
        int k = k0 + i;
        float fv;
        if (m == 0)      fv = (k < 264) ? aW0[k * H + nc] : (k == 264 ? ab0[nc] : 0.0f);
        else if (m == 1) fv = (k < 128) ? aW1[k * H + nc] : 0.0f;
        else             fv = (k < K) ? W[k * H + n] : 0.0f;
        o.u[i] = f2bf(fv);
    }
    *(u16x8*)&dst[offs[m] + n * (nb * 8) + j * 8] = o.v;
}

// ---- angle gather: x^T as B-operand, lane (ml,kq) holds x[edge ml][k].
// af[8]: kq==0 -> e2 tail (k 256..263); kq==1 -> const-1 (k=264 bias row);
// kq>=2 -> zeros.
__device__ __forceinline__ void gather_af(bf16x8 af[9],
        const float* __restrict__ e1, const float* __restrict__ e2,
        const float* __restrict__ a12, int e, int rw, int cl, int kq) {
    const float* p1 = e1 + (size_t)rw * H;
    const float* p2 = e2 + (size_t)cl * H;
#pragma unroll
    for (int f = 0; f < 8; ++f) {
        int k0 = f * 32 + kq * 8;
        const float* p = (k0 == 0) ? (a12 + (size_t)e * 8)
                       : (k0 <= 128 ? p1 + (k0 - 8) : p2 + (k0 - 136));
        af[f] = cvt8(ld4(p), ld4(p + 4));
    }
    if (kq == 0)      af[8] = cvt8(ld4(p2 + 120), ld4(p2 + 124));
    else if (kq == 1) { bf16x8 o = {(short)0x3F80, 0, 0, 0, 0, 0, 0, 0}; af[8] = o; }
    else              { bf16x8 z = {0, 0, 0, 0, 0, 0, 0, 0}; af[8] = z; }
}

// ---- angle MLP: blocked, swapped-operand MFMA, no hbuf, asm pk-f16 atomics.
// LDS = 32 KB exactly -> 4 blocks/CU (launch_bounds cap 128 VGPR, ~48 used).
__global__ __launch_bounds__(NTH, 4) void angle_mlp(
    const float* __restrict__ e1, const float* __restrict__ e2,
    const float* __restrict__ a12, const int* __restrict__ idx,
    const u16* __restrict__ wt0, const u16* __restrict__ wt1, const u16* __restrict__ wt2,
    const float* __restrict__ b1p, const float* __restrict__ b2g,
    u16* __restrict__ sums, float* __restrict__ cnt, int A)
{
    __shared__ u16 wbuf[2][128 * 64];   // 32 KB

    const int tid = threadIdx.x;
    const int lane = tid & 63;
    const int ml = lane & 15, kq = lane >> 4;
    const int w = tid >> 6;
    const int ebase = blockIdx.x * 64;           // A % 64 == 0
    const int e = ebase + w * 16 + ml;
    const int rw = idx[e];
    const int cl = idx[A + e];

    bf16x8 af[9];
    gather_af(af, e1, e2, a12, e, rw, cl, kq);

    f32x4 acc[8];
#pragma unroll
    for (int sc = 0; sc < 8; ++sc) acc[sc] = f32x4{0.f, 0.f, 0.f, 0.f};
    // L0: K=320 (264 + bias row + pad), bias b0 baked into W0 at k=264
    stream_layer_sw<5, 1>(wt0, 320, af, wbuf[0], wbuf[1], tid, ml, kq, acc);

    // transition -> L1 (in-lane; pi baked into W0-out/W1-in); b1 from global
    bf16x8 hq[4];
#pragma unroll
    for (int ks = 0; ks < 4; ++ks) hq[ks] = cvt8selu(acc[ks], acc[ks + 4]);
#pragma unroll
    for (int sc = 0; sc < 8; ++sc) acc[sc] = *(const f32x4*)&b1p[sc * 16 + kq * 4];
    // stream_layer's trailing barrier makes wbuf overwrite safe here
    preload2_layer_sw(wt1, hq, wbuf[0], wbuf[1], tid, ml, kq, acc);

    // transition -> L2 (W2 canonical out); b2 from global
#pragma unroll
    for (int ks = 0; ks < 4; ++ks) hq[ks] = cvt8selu(acc[ks], acc[ks + 4]);
#pragma unroll
    for (int sc = 0; sc < 8; ++sc) acc[sc] = *(const f32x4*)&b2g[sc * 16 + kq * 4];
    __syncthreads();                     // L1 mfma reads of wbuf done
    preload2_layer_sw(wt2, hq, wbuf[0], wbuf[1], tid, ml, kq, acc);

    // scatter (after the last barrier: no barrier ever drains an atomic).
    // lane owns edge ml; rows = features sc*16 + kq*4 + r. r5-proven asm
    // global_atomic_pk_add_f16 (clean 1x WRITE payload, no CAS fallback).
    if (kq == 0) atomicAdd(&cnt[cl], 1.0f);
    u16* dst = sums + (size_t)cl * H + kq * 4;
#pragma unroll
    for (int sc = 0; sc < 8; ++sc)
#pragma unroll
        for (int q = 0; q < 2; ++q) {
            union { __half2 h; unsigned u; } c;
            c.h = __floats2half2_rn(acc[sc][2 * q], acc[sc][2 * q + 1]);
            u16* d = dst + sc * 16 + 2 * q;
            asm volatile("global_atomic_pk_add_f16 %0, %1, off"
                         :: "v"(d), "v"(c.u) : "memory");
        }
}

// ---- edge MLP (unchanged r5 structure, f16 sums input) ----
__global__ __launch_bounds__(NTH, 3) void edge_mlp(
    const float* __restrict__ e2, const u16* __restrict__ sums,
    const float* __restrict__ cnt,
    const u16* __restrict__ wt0, const u16* __restrict__ wt1, const u16* __restrict__ wt2,
    const float* __restrict__ b0, const float* __restrict__ b1, const float* __restrict__ b2,
    float* __restrict__ out, int E2n)
{
    __shared__ u16 wbuf[2][128 * 64];
    __shared__ u16 hbuf[64 * 136];

    const int tid = threadIdx.x;
    const int lane = tid & 63;
    const int ml = lane & 15, kq = lane >> 4;
    const int w = tid >> 6;
    const int nbase = blockIdx.x * 64;
    const int node = nbase + w * 16 + ml;
    const int nc = node < E2n ? node : E2n - 1;

    const float rcp = 1.0f / fmaxf(cnt[nc], 1.0f);
    // frag f: k0 = f*32 + kq*8; k0<128 -> f16 sums*rcp | else e2[k0-128]
    bf16x8 af[8];
    {
        const u16* ps = sums + (size_t)nc * H;
        const float* p2 = e2 + (size_t)nc * H;
#pragma unroll
        for (int f = 0; f < 8; ++f) {
            int k0 = f * 32 + kq * 8;
            float4 lo, hi;
            if (k0 < 128) {
                u16x8 hv = *(const u16x8*)(ps + k0);
                lo.x = h2f(hv[0]) * rcp; lo.y = h2f(hv[1]) * rcp;
                lo.z = h2f(hv[2]) * rcp; lo.w = h2f(hv[3]) * rcp;
                hi.x = h2f(hv[4]) * rcp; hi.y = h2f(hv[5]) * rcp;
                hi.z = h2f(hv[6]) * rcp; hi.w = h2f(hv[7]) * rcp;
            } else {
                lo = ld4(p2 + (k0 - 128));
                hi = ld4(p2 + (k0 - 124));
            }
            af[f] = cvt8(lo, hi);
        }
    }

    f32x4 acc[8];
    init_acc(b0, ml, acc);
    stream_layer<4, 2>(wt0, 256, af, wbuf[0], wbuf[1], tid, ml, kq, acc);

    store_h_selu(acc, hbuf, w, ml, kq);
    __syncthreads();
    bf16x8 af1[4];
    read_af_h(hbuf, w, ml, kq, af1);
    init_acc(b1, ml, acc);
    preload2_layer(wt1, af1, wbuf[0], wbuf[1], tid, ml, kq, acc);

    __syncthreads();
    store_h_selu(acc, hbuf, w, ml, kq);
    __syncthreads();
    bf16x8 af2[4];
    read_af_h(hbuf, w, ml, kq, af2);
    init_acc(b2, ml, acc);
    preload2_layer(wt2, af2, wbuf[0], wbuf[1], tid, ml, kq, acc);

#pragma unroll
    for (int r = 0; r < 4; ++r) {
        int nrow = nbase + w * 16 + kq * 4 + r;
        if (nrow < E2n) {
            float* dst = out + (size_t)nrow * H + ml;
#pragma unroll
            for (int sc = 0; sc < 8; ++sc)
                dst[sc * 16] = acc[sc][r];
        }
    }
}

extern "C" void kernel_launch(void* const* d_in, const int* in_sizes, int n_in,
                              void* d_out, int out_size, void* d_ws, size_t ws_size,
                              hipStream_t stream)
{
    const float* e1  = (const float*)d_in[0];
    const float* e2  = (const float*)d_in[1];
    const float* a12 = (const float*)d_in[2];
    const int*   idx = (const int*)d_in[3];
    const float* aW0 = (const float*)d_in[4];
    const float* ab0 = (const float*)d_in[5];
    const float* aW1 = (const float*)d_in[6];
    const float* ab1 = (const float*)d_in[7];
    const float* aW2 = (const float*)d_in[8];
    const float* ab2 = (const float*)d_in[9];
    const float* eW0 = (const float*)d_in[10];
    const float* eb0 = (const float*)d_in[11];
    const float* eW1 = (const float*)d_in[12];
    const float* eb1 = (const float*)d_in[13];
    const float* eW2 = (const float*)d_in[14];
    const float* eb2 = (const float*)d_in[15];

    const int E2n = in_sizes[1] / H;   // 100000
    const int A   = in_sizes[2] / 8;   // 400000

    char* ws = (char*)d_ws;
    u16*   wdst   = (u16*)ws;                                // 278528 B
    u16*   sums_h = (u16*)(ws + 278528);                     // f16 [E2][128]
    float* cnt    = (float*)(ws + 278528 + (size_t)E2n * H * 2);
    float* b1p    = (float*)(ws + 278528 + (size_t)E2n * H * 2 + (size_t)E2n * 4);

    hipMemsetAsync(sums_h, 0, (size_t)E2n * H * 2 + (size_t)E2n * 4, stream);
    prep_weights<<<dim3(69), dim3(256), 0, stream>>>(
        aW0, ab0, aW1, ab1, aW2, eW0, eW1, eW2, wdst, b1p);

    angle_mlp<<<dim3(A / 64), dim3(NTH), 0, stream>>>(
        e1, e2, a12, idx, wdst + 0, wdst + 40960, wdst + 57344,
        b1p, ab2, sums_h, cnt, A);

    edge_mlp<<<dim3((E2n + 63) / 64), dim3(NTH), 0, stream>>>(
        e2, sums_h, cnt, wdst + 73728, wdst + 106496, wdst + 122880,
        eb0, eb1, eb2, (float*)d_out, E2n);
}

// Round 8
// 313.183 us; speedup vs baseline: 1.4395x; 1.4395x over previous
//
#include <hip/hip_runtime.h>
#include <hip/hip_bf16.h>
#include <hip/hip_fp16.h>

// DownEdgeMP, round 12: r5 kernel (best, 289us angle) + 2-pass gather pipeline.
// Unified model of r4-r11: angle FETCH is pinned at ~205MB (= unique gather
// data; L3 absorbs repeats) and r5 reads it at 0.71 TB/s -- a DUTY-CYCLE
// limit (gather issued only in the first ~25% of each block; r8 proved the
// HW sustains 2.4 TB/s random when requests stay in flight). Atomics (r4->r5
// halving: null), barriers, occupancy were never the wall. The swapped-layout
// scatter (r10/r11) writes through at 2x (strided per-instruction pattern,
// WRITE 212MB) and regressed; r5's lane-contiguous paired scatter is clean
// (112.5MB). So: keep r5 byte-identical, but each block runs 128 edges in
// TWO passes; pass-1's gather is prefetched as raw f32 (f=0..3 at block
// start, f=4..7 after L0; ~64 VGPR) so its HBM latency hides under pass-0's
// MLP. Pass-1 e2-tail shares f=7's cache line -> L2 hit. Gather duty ~2x.

using u16    = unsigned short;
using u16x8  = __attribute__((ext_vector_type(8))) unsigned short;
using bf16x8 = __attribute__((ext_vector_type(8))) short;
using f32x4  = __attribute__((ext_vector_type(4))) float;

constexpr int H   = 128;
constexpr int NTH = 256;

__device__ __forceinline__ u16 f2bf(float f) {          // prep only
    union { float f; unsigned u; } x; x.f = f;
    unsigned r = x.u + 0x7FFFu + ((x.u >> 16) & 1u);
    return (u16)(r >> 16);
}
__device__ __forceinline__ unsigned cvt2(float x, float y) {
    union { __hip_bfloat162 h; unsigned u; } c;
    c.h = __float22bfloat162_rn(make_float2(x, y));     // v_cvt_pk_bf16_f32
    return c.u;
}
__device__ __forceinline__ bf16x8 cvt8(float4 a, float4 b) {
    union { unsigned u[4]; bf16x8 v; } o;
    o.u[0] = cvt2(a.x, a.y); o.u[1] = cvt2(a.z, a.w);
    o.u[2] = cvt2(b.x, b.y); o.u[3] = cvt2(b.z, b.w);
    return o.v;
}
__device__ __forceinline__ float4 ld4(const float* p) { return *(const float4*)p; }
__device__ __forceinline__ float h2f(u16 u) {
    union { u16 u; __half h; } c; c.u = u;
    return __half2float(c.h);
}
__device__ __forceinline__ float selu_f(float x) {
    const float scale = 1.0507009873554804934193349852946f;
    const float sa    = 1.0507009873554805f * 1.6732632423543772848170429916717f;
    return x > 0.0f ? scale * x : sa * (__expf(x) - 1.0f);
}

// ---- weight chunk staging: 128 rows x 64 k (16 KB) ----
__device__ __forceinline__ void load_wchunk(const u16* __restrict__ wt, int KPu, int c,
                                            int tid, u16x8 st[4]) {
#pragma unroll
    for (int s = 0; s < 4; ++s) {
        int i = s * NTH + tid;                 // 0..1023
        int n = i >> 3, jj = i & 7;
        st[s] = *(const u16x8*)(wt + (size_t)n * KPu + (c * 8 + jj) * 8);
    }
}
__device__ __forceinline__ void write_wchunk(u16* wb, int tid, const u16x8 st[4]) {
#pragma unroll
    for (int s = 0; s < 4; ++s) {
        int i = s * NTH + tid;
        *(u16x8*)(wb + i * 8) = st[s];
    }
}

template<int NKS>
__device__ __forceinline__ void mfma_chunk(const u16* cur, const bf16x8* afc,
                                           int ml, int kq, f32x4 acc[8]) {
#pragma unroll
    for (int ks = 0; ks < NKS; ++ks) {
        bf16x8 a = afc[ks];
#pragma unroll
        for (int sc = 0; sc < 8; ++sc) {
            bf16x8 b = *(const bf16x8*)&cur[(sc * 16 + ml) * 64 +
                                            (((ks * 4 + kq) ^ (ml & 7)) << 3)];
            acc[sc] = __builtin_amdgcn_mfma_f32_16x16x32_bf16(a, b, acc[sc], 0, 0, 0);
        }
    }
}

// stream NCHUNK 64-K chunks through double-buffered LDS
template<int NCHUNK, int LAST_NKS>
__device__ __forceinline__ void stream_layer(const u16* __restrict__ wt, int KPu,
                                             const bf16x8* af, u16* wb0, u16* wb1,
                                             int tid, int ml, int kq, f32x4 acc[8]) {
    u16x8 st[4];
    load_wchunk(wt, KPu, 0, tid, st);
    write_wchunk(wb0, tid, st);
    __syncthreads();
#pragma unroll
    for (int c = 0; c < NCHUNK; ++c) {
        u16* cur = (c & 1) ? wb1 : wb0;
        u16* nxt = (c & 1) ? wb0 : wb1;
        if (c + 1 < NCHUNK) load_wchunk(wt, KPu, c + 1, tid, st);   // issue early
        if (c == NCHUNK - 1) mfma_chunk<LAST_NKS>(cur, af + 2 * c, ml, kq, acc);
        else                 mfma_chunk<2>(cur, af + 2 * c, ml, kq, acc);
        if (c + 1 < NCHUNK) write_wchunk(nxt, tid, st);             // write late
        __syncthreads();
    }
}

// K=128 layer: preload both 64-K chunks, single barrier
__device__ __forceinline__ void preload2_layer(const u16* __restrict__ wt,
                                               const bf16x8* af, u16* wb0, u16* wb1,
                                               int tid, int ml, int kq, f32x4 acc[8]) {
    u16x8 s0[4], s1[4];
    load_wchunk(wt, 128, 0, tid, s0);
    load_wchunk(wt, 128, 1, tid, s1);
    write_wchunk(wb0, tid, s0);
    write_wchunk(wb1, tid, s1);
    __syncthreads();
    mfma_chunk<2>(wb0, af + 0, ml, kq, acc);
    mfma_chunk<2>(wb1, af + 2, ml, kq, acc);
}

__device__ __forceinline__ void init_acc(const float* __restrict__ b, int ml, f32x4 acc[8]) {
#pragma unroll
    for (int sc = 0; sc < 8; ++sc) {
        float bv = b[sc * 16 + ml];
        acc[sc] = f32x4{bv, bv, bv, bv};
    }
}

// SELU(acc) -> bf16 -> hbuf[64][136] (padded stride: b128 reads hit 8-cyc floor)
__device__ __forceinline__ void store_h_selu(const f32x4 acc[8], u16* hbuf,
                                             int w, int ml, int kq) {
#pragma unroll
    for (int sc = 0; sc < 8; ++sc)
#pragma unroll
        for (int r = 0; r < 4; r += 2) {
            unsigned u = cvt2(selu_f(acc[sc][r]), selu_f(acc[sc][r + 1]));
            int rowb = w * 16 + kq * 4 + r;
            hbuf[rowb * 136 + sc * 16 + ml]       = (u16)u;
            hbuf[(rowb + 1) * 136 + sc * 16 + ml] = (u16)(u >> 16);
        }
}
__device__ __forceinline__ void read_af_h(const u16* hbuf, int w, int ml, int kq,
                                          bf16x8 af[4]) {
#pragma unroll
    for (int f = 0; f < 4; ++f)            // col = f*32 + kq*8
        af[f] = *(const bf16x8*)&hbuf[(w * 16 + ml) * 136 + f * 32 + kq * 8];
}

// ---- prep: fp32 W[K][128] -> bf16 W^T[128][KP], 16B-block XOR(n&7) swizzle ----
__global__ void prep_weights(const float* __restrict__ aW0, const float* __restrict__ aW1,
                             const float* __restrict__ aW2, const float* __restrict__ eW0,
                             const float* __restrict__ eW1, const float* __restrict__ eW2,
                             u16* __restrict__ dst)
{
    int t = blockIdx.x * 256 + threadIdx.x;
    const int nbs[6]  = {40, 16, 16, 32, 16, 16};
    const int Ks[6]   = {264, 128, 128, 256, 128, 128};
    const int offs[6] = {0, 40960, 57344, 73728, 106496, 122880};
    const float* Ws[6] = {aW0, aW1, aW2, eW0, eW1, eW2};
    int m = 0, rem = t;
    for (m = 0; m < 6; ++m) { int c = 128 * nbs[m]; if (rem < c) break; rem -= c; }
    if (m >= 6) return;
    const int nb = nbs[m];
    const int n = rem / nb, j = rem % nb;
    const int c = j >> 3, jj = j & 7;
    const int kb = jj ^ (n & 7);
    const int k0 = c * 64 + kb * 8;
    const int K = Ks[m];
    const float* W = Ws[m];
    union { u16 u[8]; u16x8 v; } o;
#pragma unroll
    for (int i = 0; i < 8; ++i) {
        int k = k0 + i;
        o.u[i] = (k < K) ? f2bf(W[k * H + n]) : (u16)0;
    }
    *(u16x8*)&dst[offs[m] + n * (nb * 8) + j * 8] = o.v;
}

// ---- angle MLP pass: full 3-layer MLP for 64 edges (r5 barrier structure) ----
__device__ __forceinline__ void angle_pass(const bf16x8 af[9],
        const u16* __restrict__ wt0, const u16* __restrict__ wt1,
        const u16* __restrict__ wt2,
        const float* __restrict__ b0, const float* __restrict__ b1,
        const float* __restrict__ b2,
        u16* wbuf0, u16* wbuf1, u16* hbuf,
        int tid, int w, int ml, int kq, f32x4 acc[8])
{
    init_acc(b0, ml, acc);
    stream_layer<5, 1>(wt0, 320, af, wbuf0, wbuf1, tid, ml, kq, acc);

    store_h_selu(acc, hbuf, w, ml, kq);
    __syncthreads();
    bf16x8 af1[4];
    read_af_h(hbuf, w, ml, kq, af1);
    init_acc(b1, ml, acc);
    preload2_layer(wt1, af1, wbuf0, wbuf1, tid, ml, kq, acc);

    __syncthreads();                    // h1 reads + W1 B-reads done
    store_h_selu(acc, hbuf, w, ml, kq);
    __syncthreads();
    bf16x8 af2[4];
    read_af_h(hbuf, w, ml, kq, af2);
    init_acc(b2, ml, acc);
    preload2_layer(wt2, af2, wbuf0, wbuf1, tid, ml, kq, acc);
}

// r5's paired lane-contiguous pk-f16 scatter (clean 1x write-through pattern)
__device__ __forceinline__ void scatter_pass(const f32x4 acc[8],
        const int* __restrict__ idx, u16* __restrict__ sums,
        int A, int ebase, int w, int ml, int kq)
{
    const int rb = (ml & 1) * 2;
    const int i0 = A + ebase + w * 16 + kq * 4;
    const int clr0 = idx[i0 + rb];
    const int clr1 = idx[i0 + rb + 1];
#pragma unroll
    for (int sc = 0; sc < 8; ++sc) {
        float p0 = __shfl_xor(acc[sc][0], 1);
        float p1 = __shfl_xor(acc[sc][1], 1);
        float p2 = __shfl_xor(acc[sc][2], 1);
        float p3 = __shfl_xor(acc[sc][3], 1);
        float o0 = acc[sc][rb], o1 = acc[sc][rb + 1];
        float q0 = (ml & 1) ? p2 : p0;          // partner col value, my rows
        float q1 = (ml & 1) ? p3 : p1;
        float l0 = (ml & 1) ? q0 : o0, h0 = (ml & 1) ? o0 : q0;
        float l1 = (ml & 1) ? q1 : o1, h1 = (ml & 1) ? o1 : q1;
        union { __half2 h; unsigned u; } c0, c1;
        c0.h = __floats2half2_rn(l0, h0);
        c1.h = __floats2half2_rn(l1, h1);
        u16* d0 = sums + (size_t)clr0 * H + sc * 16 + (ml & ~1);
        u16* d1 = sums + (size_t)clr1 * H + sc * 16 + (ml & ~1);
        asm volatile("global_atomic_pk_add_f16 %0, %1, off" :: "v"(d0), "v"(c0.u) : "memory");
        asm volatile("global_atomic_pk_add_f16 %0, %1, off" :: "v"(d1), "v"(c1.u) : "memory");
    }
}

// ---- angle MLP: 128 edges/block, 2 passes; pass-1 gather prefetched ----
__global__ __launch_bounds__(NTH, 3) void angle_mlp(
    const float* __restrict__ e1, const float* __restrict__ e2,
    const float* __restrict__ a12, const int* __restrict__ idx,
    const u16* __restrict__ wt0, const u16* __restrict__ wt1, const u16* __restrict__ wt2,
    const float* __restrict__ b0, const float* __restrict__ b1, const float* __restrict__ b2,
    u16* __restrict__ sums, float* __restrict__ cnt, int A)
{
    __shared__ u16 wbuf[2][128 * 64];   // 32 KB
    __shared__ u16 hbuf[64 * 136];      // 17 KB

    const int tid = threadIdx.x;
    const int lane = tid & 63;
    const int ml = lane & 15, kq = lane >> 4;
    const int w = tid >> 6;
    const int ebase = blockIdx.x * 128;          // A % 128 == 0
    const int ea = ebase + w * 16 + ml;          // pass-0 edge
    const int eb = ea + 64;                      // pass-1 edge
    const int rwa = idx[ea], cla = idx[A + ea];
    const int rwb = idx[eb], clb = idx[A + eb];
    if (kq == 0) { atomicAdd(&cnt[cla], 1.0f); atomicAdd(&cnt[clb], 1.0f); }

    // ---- pass-0 gather -> af (r5 pattern: cvt as loads land) ----
    // frag f: k0=f*32+kq*8; k0==0 -> a12 | 8..128 -> e1 | 136..256 -> e2 | tail
    bf16x8 af[9];
    {
        const float* p1 = e1 + (size_t)rwa * H;
        const float* p2 = e2 + (size_t)cla * H;
#pragma unroll
        for (int f = 0; f < 8; ++f) {
            int k0 = f * 32 + kq * 8;
            const float* p = (k0 == 0) ? (a12 + (size_t)ea * 8)
                           : (k0 <= 128 ? p1 + (k0 - 8) : p2 + (k0 - 136));
            af[f] = cvt8(ld4(p), ld4(p + 4));
        }
        if (kq == 0) af[8] = cvt8(ld4(p2 + 120), ld4(p2 + 124));   // k0=256
        else { bf16x8 z = {0,0,0,0,0,0,0,0}; af[8] = z; }          // k0>=264
    }

    // ---- prefetch pass-1 gather, first half (a12 / e1): f=0..3 (32 VGPR) ----
    float4 raw1[16];
    {
        const float* p1 = e1 + (size_t)rwb * H;
#pragma unroll
        for (int f = 0; f < 4; ++f) {
            int k0 = f * 32 + kq * 8;
            const float* p = (k0 == 0) ? (a12 + (size_t)eb * 8) : (p1 + (k0 - 8));
            raw1[2 * f]     = ld4(p);
            raw1[2 * f + 1] = ld4(p + 4);
        }
    }

    // ---- pass 0: L0 ----
    f32x4 acc[8];
    init_acc(b0, ml, acc);
    stream_layer<5, 1>(wt0, 320, af, wbuf[0], wbuf[1], tid, ml, kq, acc);

    // ---- prefetch pass-1 gather, second half (e1 tail / e2): f=4..7 ----
    {
        const float* p1 = e1 + (size_t)rwb * H;
        const float* p2 = e2 + (size_t)clb * H;
#pragma unroll
        for (int f = 4; f < 8; ++f) {
            int k0 = f * 32 + kq * 8;
            const float* p = (k0 <= 128) ? (p1 + (k0 - 8)) : (p2 + (k0 - 136));
            raw1[2 * f]     = ld4(p);
            raw1[2 * f + 1] = ld4(p + 4);
        }
    }

    // ---- pass 0: L1 + L2 (r5 barrier structure) ----
    store_h_selu(acc, hbuf, w, ml, kq);
    __syncthreads();
    {
        bf16x8 af1[4];
        read_af_h(hbuf, w, ml, kq, af1);
        init_acc(b1, ml, acc);
        preload2_layer(wt1, af1, wbuf[0], wbuf[1], tid, ml, kq, acc);
    }
    __syncthreads();
    store_h_selu(acc, hbuf, w, ml, kq);
    __syncthreads();
    {
        bf16x8 af2[4];
        read_af_h(hbuf, w, ml, kq, af2);
        init_acc(b2, ml, acc);
        preload2_layer(wt2, af2, wbuf[0], wbuf[1], tid, ml, kq, acc);
    }
    scatter_pass(acc, idx, sums, A, ebase, w, ml, kq);

    __syncthreads();                    // wbuf/hbuf safe for pass 1

    // ---- pass 1: convert prefetched raws; tail is an L2 hit (f=7's line) ----
    {
        const float* p2 = e2 + (size_t)clb * H;
#pragma unroll
        for (int f = 0; f < 8; ++f) af[f] = cvt8(raw1[2 * f], raw1[2 * f + 1]);
        if (kq == 0) af[8] = cvt8(ld4(p2 + 120), ld4(p2 + 124));
        else { bf16x8 z = {0,0,0,0,0,0,0,0}; af[8] = z; }
    }
    angle_pass(af, wt0, wt1, wt2, b0, b1, b2,
               wbuf[0], wbuf[1], hbuf, tid, w, ml, kq, acc);
    scatter_pass(acc, idx, sums, A, ebase + 64, w, ml, kq);
}

// ---- edge MLP (unchanged r5 structure, f16 sums input) ----
__global__ __launch_bounds__(NTH, 3) void edge_mlp(
    const float* __restrict__ e2, const u16* __restrict__ sums,
    const float* __restrict__ cnt,
    const u16* __restrict__ wt0, const u16* __restrict__ wt1, const u16* __restrict__ wt2,
    const float* __restrict__ b0, const float* __restrict__ b1, const float* __restrict__ b2,
    float* __restrict__ out, int E2n)
{
    __shared__ u16 wbuf[2][128 * 64];
    __shared__ u16 hbuf[64 * 136];

    const int tid = threadIdx.x;
    const int lane = tid & 63;
    const int ml = lane & 15, kq = lane >> 4;
    const int w = tid >> 6;
    const int nbase = blockIdx.x * 64;
    const int node = nbase + w * 16 + ml;
    const int nc = node < E2n ? node : E2n - 1;

    const float rcp = 1.0f / fmaxf(cnt[nc], 1.0f);
    // frag f: k0 = f*32 + kq*8; k0<128 -> f16 sums*rcp | else e2[k0-128]
    bf16x8 af[8];
    {
        const u16* ps = sums + (size_t)nc * H;
        const float* p2 = e2 + (size_t)nc * H;
#pragma unroll
        for (int f = 0; f < 8; ++f) {
            int k0 = f * 32 + kq * 8;
            float4 lo, hi;
            if (k0 < 128) {
                u16x8 hv = *(const u16x8*)(ps + k0);
                lo.x = h2f(hv[0]) * rcp; lo.y = h2f(hv[1]) * rcp;
                lo.z = h2f(hv[2]) * rcp; lo.w = h2f(hv[3]) * rcp;
                hi.x = h2f(hv[4]) * rcp; hi.y = h2f(hv[5]) * rcp;
                hi.z = h2f(hv[6]) * rcp; hi.w = h2f(hv[7]) * rcp;
            } else {
                lo = ld4(p2 + (k0 - 128));
                hi = ld4(p2 + (k0 - 124));
            }
            af[f] = cvt8(lo, hi);
        }
    }

    f32x4 acc[8];
    init_acc(b0, ml, acc);
    stream_layer<4, 2>(wt0, 256, af, wbuf[0], wbuf[1], tid, ml, kq, acc);

    store_h_selu(acc, hbuf, w, ml, kq);
    __syncthreads();
    bf16x8 af1[4];
    read_af_h(hbuf, w, ml, kq, af1);
    init_acc(b1, ml, acc);
    preload2_layer(wt1, af1, wbuf[0], wbuf[1], tid, ml, kq, acc);

    __syncthreads();
    store_h_selu(acc, hbuf, w, ml, kq);
    __syncthreads();
    bf16x8 af2[4];
    read_af_h(hbuf, w, ml, kq, af2);
    init_acc(b2, ml, acc);
    preload2_layer(wt2, af2, wbuf[0], wbuf[1], tid, ml, kq, acc);

#pragma unroll
    for (int r = 0; r < 4; ++r) {
        int nrow = nbase + w * 16 + kq * 4 + r;
        if (nrow < E2n) {
            float* dst = out + (size_t)nrow * H + ml;
#pragma unroll
            for (int sc = 0; sc < 8; ++sc)
                dst[sc * 16] = acc[sc][r];
        }
    }
}

extern "C" void kernel_launch(void* const* d_in, const int* in_sizes, int n_in,
                              void* d_out, int out_size, void* d_ws, size_t ws_size,
                              hipStream_t stream)
{
    const float* e1  = (const float*)d_in[0];
    const float* e2  = (const float*)d_in[1];
    const float* a12 = (const float*)d_in[2];
    const int*   idx = (const int*)d_in[3];
    const float* aW0 = (const float*)d_in[4];
    const float* ab0 = (const float*)d_in[5];
    const float* aW1 = (const float*)d_in[6];
    const float* ab1 = (const float*)d_in[7];
    const float* aW2 = (const float*)d_in[8];
    const float* ab2 = (const float*)d_in[9];
    const float* eW0 = (const float*)d_in[10];
    const float* eb0 = (const float*)d_in[11];
    const float* eW1 = (const float*)d_in[12];
    const float* eb1 = (const float*)d_in[13];
    const float* eW2 = (const float*)d_in[14];
    const float* eb2 = (const float*)d_in[15];

    const int E2n = in_sizes[1] / H;   // 100000
    const int A   = in_sizes[2] / 8;   // 400000

    char* ws = (char*)d_ws;
    u16*   wdst   = (u16*)ws;                                // 278528 B
    u16*   sums_h = (u16*)(ws + 278528);                     // f16 [E2][128]
    float* cnt    = (float*)(ws + 278528 + (size_t)E2n * H * 2);

    hipMemsetAsync(sums_h, 0, (size_t)E2n * H * 2 + (size_t)E2n * 4, stream);
    prep_weights<<<dim3(68), dim3(256), 0, stream>>>(aW0, aW1, aW2, eW0, eW1, eW2, wdst);

    angle_mlp<<<dim3(A / 128), dim3(NTH), 0, stream>>>(
        e1, e2, a12, idx, wdst + 0, wdst + 40960, wdst + 57344,
        ab0, ab1, ab2, sums_h, cnt, A);

    edge_mlp<<<dim3((E2n + 63) / 64), dim3(NTH), 0, stream>>>(
        e2, sums_h, cnt, wdst + 73728, wdst + 106496, wdst + 122880,
        eb0, eb1, eb2, (float*)d_out, E2n);
}